// Round 7
// baseline (65.004 us; speedup 1.0000x reference)
//
#include <hip/hip_runtime.h>

// VQ nearest-codebook: x [16,64,64,64] NCHW fp32, emb [512,64] fp32.
// out = concat(one_hot [65536,512] f32, quantized [16,64,64,64] f32).
//
// Round-7 = round-6 structure with a store-queue-decoupled schedule:
//  * main-loop barriers are raw s_barrier + lgkmcnt(0) (NO vmcnt drain;
//    __syncthreads would retire the zero-store burst every chunk).
//  * esq lives in LDS (lgkm domain) so eq reads never wait on stores.
//  * per chunk: issue next-chunk prefetch loads BEFORE the zero stores
//    (vmcnt retires in issue order: older loads complete without draining
//    younger stores), pinned with sched_barrier(0).
//  * the only vmcnt(0) drain is the final __syncthreads before the 1.0
//    scatter (mandatory: zeros must be retired before the scatter).

constexpr int D    = 64;
constexpr int K    = 512;
constexpr int N    = 65536;
constexpr int HW   = 4096;
constexpr int TPB  = 256;
constexpr int PIXB = 64;
constexpr int NCHUNK = 4;            // 128 codes per chunk

typedef __attribute__((ext_vector_type(8))) short bf16x8;
typedef __attribute__((ext_vector_type(4))) short short4v;
typedef __attribute__((ext_vector_type(4))) float f32x4;

__device__ inline unsigned short f2bf(float f) {           // RNE f32->bf16
    unsigned u = __builtin_bit_cast(unsigned, f);
    unsigned r = u + 0x7fffu + ((u >> 16) & 1u);
    return (unsigned short)(r >> 16);
}
__device__ inline float bf2f(unsigned short h) {
    unsigned u = ((unsigned)h) << 16;
    return __builtin_bit_cast(float, u);
}

// barrier WITHOUT vmcnt drain: LDS-visibility only.
__device__ inline void bar_lds() {
    asm volatile("s_waitcnt lgkmcnt(0)" ::: "memory");
    __builtin_amdgcn_sched_barrier(0);
    __builtin_amdgcn_s_barrier();
    __builtin_amdgcn_sched_barrier(0);
}

// cheap top-2 update (min/max sort; ties keep earlier code)
__device__ inline void top2u(float s, int code, float& bs, float& ss, int& bi, int& si) {
    bool c1 = s < bs;
    bool c2 = s < ss;
    float mx = fmaxf(bs, s);
    bs = fminf(bs, s);
    ss = fminf(ss, mx);
    si = c1 ? bi : (c2 ? code : si);
    bi = c1 ? code : bi;
}
// insert with explicit index tie-break (cross-lane/cross-wave merges)
__device__ inline void top2_ins(float os, int oi, float& bs, float& ss, int& bi, int& si) {
    bool c1 = (os < bs) || (os == bs && oi < bi);
    bool c2 = (os < ss) || (os == ss && oi < si);
    ss = c1 ? bs : (c2 ? os : ss);
    si = c1 ? bi : (c2 ? oi : si);
    bs = c1 ? os : bs;
    bi = c1 ? oi : bi;
}

// ---------------- prep: emb -> frag-ordered hi/lo bf16 + e_sq ----------------
// ebuf shorts: chunk*16384 + sec*4096 + tile*512 + g*128 + cl*8 + j
__global__ __launch_bounds__(TPB) void vq_prep(
    const float* __restrict__ emb, short* __restrict__ ebuf, float* __restrict__ esq)
{
    const int t    = blockIdx.x * TPB + threadIdx.x;   // 8192 threads
    const int code = t >> 4;
    const int q    = t & 15;
    const int d0   = q * 4;
    float4 f = ((const float4*)emb)[t];
    unsigned short h0 = f2bf(f.x), h1 = f2bf(f.y), h2 = f2bf(f.z), h3 = f2bf(f.w);
    short4v hv = { (short)h0, (short)h1, (short)h2, (short)h3 };
    short4v lv = { (short)f2bf(f.x - bf2f(h0)), (short)f2bf(f.y - bf2f(h1)),
                   (short)f2bf(f.z - bf2f(h2)), (short)f2bf(f.w - bf2f(h3)) };
    const int chunk = code >> 7, cc = code & 127, tile = cc >> 4, cl = cc & 15;
    const int g = (d0 & 31) >> 3, j0 = d0 & 7, secH = (d0 >= 32) ? 1 : 0;
    const int base = chunk * 16384 + tile * 512 + g * 128 + cl * 8 + j0;
    *(short4v*)&ebuf[base + secH * 4096]       = hv;
    *(short4v*)&ebuf[base + (2 + secH) * 4096] = lv;
    float pe = f.x * f.x + f.y * f.y + f.z * f.z + f.w * f.w;
    pe += __shfl_xor(pe, 1);
    pe += __shfl_xor(pe, 2);
    pe += __shfl_xor(pe, 4);
    pe += __shfl_xor(pe, 8);
    if (q == 0) esq[code] = pe;
}

// ---------------- main ----------------
__global__ __launch_bounds__(TPB, 4) void vq_main(
    const float* __restrict__ x, const float* __restrict__ emb,
    const short* __restrict__ ebuf, const float* __restrict__ esq,
    float* __restrict__ enc, float* __restrict__ quant)
{
    __shared__ short s_e[16384];                  // 32 KB chunk buffer
    __shared__ float s_esq[K];                    // 2 KB (lgkm-domain eq reads)
    __shared__ float s_tbs[2][PIXB], s_tss[2][PIXB];
    __shared__ int   s_tbi[2][PIXB], s_tsi[2][PIXB];
    __shared__ int   s_idx[PIXB];

    const int tid  = threadIdx.x;
    const int lane = tid & 63;
    const int wave = __builtin_amdgcn_readfirstlane(tid >> 6);
    const int g    = lane >> 4;
    const int cl   = lane & 15;
    const int ph   = wave & 1;                    // pixel half (32 px)
    const int kh   = wave >> 1;                   // K half (tiles 0-3 / 4-7)
    const int wloc = ph * 32;

    const int pixbase = blockIdx.x * PIXB;
    const int b   = pixbase >> 12;
    const int hw0 = pixbase & (HW - 1);
    const float* xb = x + (size_t)b * D * HW;

    // ---- prologue loads: x (oldest), esq, chunk-0 prefetch. NO stores yet. ----
    float xv0[16], xv1[16];
    #pragma unroll
    for (int j = 0; j < 8; ++j) {
        const size_t o0 = (size_t)(g * 8 + j) * HW + hw0 + wloc + cl;
        const size_t o1 = (size_t)(32 + g * 8 + j) * HW + hw0 + wloc + cl;
        xv0[j]     = xb[o0];       xv0[8 + j] = xb[o1];
        xv1[j]     = xb[o0 + 16];  xv1[8 + j] = xb[o1 + 16];
    }
    const float eq_a = esq[tid];
    const float eq_b = esq[tid + 256];

    const bf16x8* gsrc = (const bf16x8*)ebuf;     // 16B units; chunk stride 2048
    bf16x8 stg[8];
    #pragma unroll
    for (int i = 0; i < 8; ++i) stg[i] = gsrc[i * 256 + tid];

    // esq -> LDS (waits only its own loads; counted vmcnt, no stores queued)
    s_esq[tid]       = eq_a;
    s_esq[tid + 256] = eq_b;

    // ---- pack A fragments hi/lo (waits x loads; stg stays in flight) ----
    bf16x8 a0h0, a0h1, a0l0, a0l1, a1h0, a1h1, a1l0, a1l1;
    #pragma unroll
    for (int j = 0; j < 8; ++j) {
        unsigned short h;
        h = f2bf(xv0[j]);     a0h0[j] = (short)h; a0l0[j] = (short)f2bf(xv0[j]     - bf2f(h));
        h = f2bf(xv0[8 + j]); a0h1[j] = (short)h; a0l1[j] = (short)f2bf(xv0[8 + j] - bf2f(h));
        h = f2bf(xv1[j]);     a1h0[j] = (short)h; a1l0[j] = (short)f2bf(xv1[j]     - bf2f(h));
        h = f2bf(xv1[8 + j]); a1h1[j] = (short)h; a1l1[j] = (short)f2bf(xv1[8 + j] - bf2f(h));
    }

    float bs0[4], ss0[4], bs1[4], ss1[4];
    int   bi0[4], si0[4], bi1[4], si1[4];
    #pragma unroll
    for (int r = 0; r < 4; ++r) {
        bs0[r] = ss0[r] = bs1[r] = ss1[r] = 3.4e38f;
        bi0[r] = si0[r] = bi1[r] = si1[r] = 0x7fffffff;
    }

    bf16x8* se8 = (bf16x8*)s_e;
    float4* encb4 = (float4*)(enc + (size_t)pixbase * K);
    const float4 z4 = {0.f, 0.f, 0.f, 0.f};

    for (int chunk = 0; chunk < NCHUNK; ++chunk) {
        // ---- stage regs -> LDS (conflict-free contiguous b128) ----
        #pragma unroll
        for (int i = 0; i < 8; ++i) se8[i * 256 + tid] = stg[i];
        bar_lds();                                 // LDS visible; NO store drain

        // ---- issue next-chunk prefetch FIRST (older than this chunk's stores) ----
        if (chunk + 1 < NCHUNK) {
            #pragma unroll
            for (int i = 0; i < 8; ++i)
                stg[i] = gsrc[(chunk + 1) * 2048 + i * 256 + tid];
        }
        __builtin_amdgcn_sched_barrier(0);
        // ---- then this chunk's one-hot zero slice (32 KB/block, fire-and-forget) ----
        #pragma unroll
        for (int it = 0; it < 8; ++it)
            encb4[chunk * 2048 + it * 256 + tid] = z4;
        __builtin_amdgcn_sched_barrier(0);

        // ---- compute 4 tiles (LDS/MFMA/VALU only; stores drain underneath) ----
        #pragma unroll
        for (int tt = 0; tt < 4; ++tt) {
            const int t8 = kh * 4 + tt;
            const short* pb = s_e + t8 * 512 + g * 128 + cl * 8;
            bf16x8 bh0 = *(const bf16x8*)pb;
            bf16x8 bh1 = *(const bf16x8*)(pb + 4096);
            bf16x8 bl0 = *(const bf16x8*)(pb + 8192);
            bf16x8 bl1 = *(const bf16x8*)(pb + 12288);
            f32x4 c0 = {0.f, 0.f, 0.f, 0.f};
            f32x4 c1 = {0.f, 0.f, 0.f, 0.f};
            c0 = __builtin_amdgcn_mfma_f32_16x16x32_bf16(a0h0, bh0, c0, 0, 0, 0);
            c1 = __builtin_amdgcn_mfma_f32_16x16x32_bf16(a1h0, bh0, c1, 0, 0, 0);
            c0 = __builtin_amdgcn_mfma_f32_16x16x32_bf16(a0h1, bh1, c0, 0, 0, 0);
            c1 = __builtin_amdgcn_mfma_f32_16x16x32_bf16(a1h1, bh1, c1, 0, 0, 0);
            c0 = __builtin_amdgcn_mfma_f32_16x16x32_bf16(a0l0, bh0, c0, 0, 0, 0);
            c1 = __builtin_amdgcn_mfma_f32_16x16x32_bf16(a1l0, bh0, c1, 0, 0, 0);
            c0 = __builtin_amdgcn_mfma_f32_16x16x32_bf16(a0l1, bh1, c0, 0, 0, 0);
            c1 = __builtin_amdgcn_mfma_f32_16x16x32_bf16(a1l1, bh1, c1, 0, 0, 0);
            c0 = __builtin_amdgcn_mfma_f32_16x16x32_bf16(a0h0, bl0, c0, 0, 0, 0);
            c1 = __builtin_amdgcn_mfma_f32_16x16x32_bf16(a1h0, bl0, c1, 0, 0, 0);
            c0 = __builtin_amdgcn_mfma_f32_16x16x32_bf16(a0h1, bl1, c0, 0, 0, 0);
            c1 = __builtin_amdgcn_mfma_f32_16x16x32_bf16(a1h1, bl1, c1, 0, 0, 0);
            const int code = chunk * 128 + t8 * 16 + cl;
            const float eq = s_esq[code];          // lgkm-domain: no store wait
            #pragma unroll
            for (int r = 0; r < 4; ++r) {
                top2u(fmaf(-2.0f, c0[r], eq), code, bs0[r], ss0[r], bi0[r], si0[r]);
                top2u(fmaf(-2.0f, c1[r], eq), code, bs1[r], ss1[r], bi1[r], si1[r]);
            }
        }
        bar_lds();                                 // reads done before next overwrite
    }

    // ---- cross-lane top-2 merge (over cl within each g-group) ----
    #pragma unroll
    for (int r = 0; r < 4; ++r) {
        for (int m = 1; m <= 8; m <<= 1) {
            float obs, oss; int obi, osi;
            obs = __shfl_xor(bs0[r], m); obi = __shfl_xor(bi0[r], m);
            oss = __shfl_xor(ss0[r], m); osi = __shfl_xor(si0[r], m);
            top2_ins(obs, obi, bs0[r], ss0[r], bi0[r], si0[r]);
            top2_ins(oss, osi, bs0[r], ss0[r], bi0[r], si0[r]);
            obs = __shfl_xor(bs1[r], m); obi = __shfl_xor(bi1[r], m);
            oss = __shfl_xor(ss1[r], m); osi = __shfl_xor(si1[r], m);
            top2_ins(obs, obi, bs1[r], ss1[r], bi1[r], si1[r]);
            top2_ins(oss, osi, bs1[r], ss1[r], bi1[r], si1[r]);
        }
    }
    if (cl == 0) {
        #pragma unroll
        for (int r = 0; r < 4; ++r) {
            const int p0 = wloc + g * 4 + r;          // C/D row = (lane>>4)*4+reg
            s_tbs[kh][p0] = bs0[r]; s_tss[kh][p0] = ss0[r];
            s_tbi[kh][p0] = bi0[r]; s_tsi[kh][p0] = si0[r];
            const int p1 = p0 + 16;
            s_tbs[kh][p1] = bs1[r]; s_tss[kh][p1] = ss1[r];
            s_tbi[kh][p1] = bi1[r]; s_tsi[kh][p1] = si1[r];
        }
    }
    bar_lds();                                     // publish merges; still no drain

    // ---- combine K halves + fp64 refinement of near-ties ----
    if (tid < PIXB) {
        float bs = s_tbs[0][tid], ss = s_tss[0][tid];
        int   bi = s_tbi[0][tid], si = s_tsi[0][tid];
        top2_ins(s_tbs[1][tid], s_tbi[1][tid], bs, ss, bi, si);
        top2_ins(s_tss[1][tid], s_tsi[1][tid], bs, ss, bi, si);
        int fin = bi;
        if (ss - bs < 0.125f) {
            const float* xq = xb + hw0 + tid;
            const float* e0 = emb + (size_t)bi * D;
            const float* e1 = emb + (size_t)si * D;
            double sa = 0.0, sb = 0.0;
            for (int d = 0; d < D; ++d) {
                double xvv = (double)xq[(size_t)d * HW];
                double ev0 = (double)e0[d];
                double ev1 = (double)e1[d];
                sa += ev0 * (ev0 - 2.0 * xvv);
                sb += ev1 * (ev1 - 2.0 * xvv);
            }
            if (sb < sa || (sb == sa && si < bi)) fin = si;
        }
        s_idx[tid] = fin;
    }
    __syncthreads();   // THE drain: all zero stores retired + s_idx visible

    // ---- 1.0 scatter ----
    if (tid < PIXB)
        enc[(size_t)(pixbase + tid) * K + s_idx[tid]] = 1.0f;

    // ---- quant writes: coalesced per-channel segments ----
    {
        const int p   = tid & 63;
        const int ch0 = (tid >> 6) * 16;
        const int id  = s_idx[p];
        float* qb = quant + (size_t)b * D * HW + hw0 + p;
        #pragma unroll
        for (int j = 0; j < 16; ++j)
            qb[(size_t)(ch0 + j) * HW] = emb[(size_t)id * D + ch0 + j];
    }
}

extern "C" void kernel_launch(void* const* d_in, const int* in_sizes, int n_in,
                              void* d_out, int out_size, void* d_ws, size_t ws_size,
                              hipStream_t stream)
{
    const float* x   = (const float*)d_in[0];
    const float* emb = (const float*)d_in[1];
    float* enc   = (float*)d_out;
    float* quant = (float*)d_out + (size_t)N * K;

    short* ebuf = (short*)d_ws;                          // 128 KB frag-ordered hi/lo
    float* esq  = (float*)(ebuf + (size_t)K * D * 2);    // 2 KB

    hipLaunchKernelGGL(vq_prep, dim3(K * D / 4 / TPB), dim3(TPB), 0, stream,
                       emb, ebuf, esq);
    hipLaunchKernelGGL(vq_main, dim3(N / PIXB), dim3(TPB), 0, stream,
                       x, emb, ebuf, esq, enc, quant);
}

// Round 8
// 60.803 us; speedup vs baseline: 1.0691x; 1.0691x over previous
//
#include <hip/hip_runtime.h>

// VQ nearest-codebook: x [16,64,64,64] NCHW fp32, emb [512,64] fp32.
// out = concat(one_hot [65536,512] f32, quantized [16,64,64,64] f32).
//
// Round-8 = round-6 skeleton (per-chunk __syncthreads drains = store PACING,
// keeps dirty zero-lines L2-resident; r7 proved removing them causes 60MB
// write amplification) + safe r7 bits (esq in LDS; prefetch issued BEFORE
// zero stores so load-waits never drain the store burst) + NEW: per-CU phase
// stagger — co-resident blocks (bid>>8 differs) rotate chunk order so
// compute/drain windows interleave across the CU instead of colliding
// chip-wide.

constexpr int D    = 64;
constexpr int K    = 512;
constexpr int N    = 65536;
constexpr int HW   = 4096;
constexpr int TPB  = 256;
constexpr int PIXB = 64;
constexpr int NCHUNK = 4;            // 128 codes per chunk

typedef __attribute__((ext_vector_type(8))) short bf16x8;
typedef __attribute__((ext_vector_type(4))) short short4v;
typedef __attribute__((ext_vector_type(4))) float f32x4;

__device__ inline unsigned short f2bf(float f) {           // RNE f32->bf16
    unsigned u = __builtin_bit_cast(unsigned, f);
    unsigned r = u + 0x7fffu + ((u >> 16) & 1u);
    return (unsigned short)(r >> 16);
}
__device__ inline float bf2f(unsigned short h) {
    unsigned u = ((unsigned)h) << 16;
    return __builtin_bit_cast(float, u);
}

// cheap top-2 update (min/max sort; ties keep earlier-seen code — exact ties
// are resolved later by the fp64 refine which has an index tie-break)
__device__ inline void top2u(float s, int code, float& bs, float& ss, int& bi, int& si) {
    bool c1 = s < bs;
    bool c2 = s < ss;
    float mx = fmaxf(bs, s);
    bs = fminf(bs, s);
    ss = fminf(ss, mx);
    si = c1 ? bi : (c2 ? code : si);
    bi = c1 ? code : bi;
}
// insert with explicit index tie-break (cross-lane/cross-wave merges)
__device__ inline void top2_ins(float os, int oi, float& bs, float& ss, int& bi, int& si) {
    bool c1 = (os < bs) || (os == bs && oi < bi);
    bool c2 = (os < ss) || (os == ss && oi < si);
    ss = c1 ? bs : (c2 ? os : ss);
    si = c1 ? bi : (c2 ? oi : si);
    bs = c1 ? os : bs;
    bi = c1 ? oi : bi;
}

// ---------------- prep: emb -> frag-ordered hi/lo bf16 + e_sq ----------------
// ebuf shorts: chunk*16384 + sec*4096 + tile*512 + g*128 + cl*8 + j
__global__ __launch_bounds__(TPB) void vq_prep(
    const float* __restrict__ emb, short* __restrict__ ebuf, float* __restrict__ esq)
{
    const int t    = blockIdx.x * TPB + threadIdx.x;   // 8192 threads
    const int code = t >> 4;
    const int q    = t & 15;
    const int d0   = q * 4;
    float4 f = ((const float4*)emb)[t];
    unsigned short h0 = f2bf(f.x), h1 = f2bf(f.y), h2 = f2bf(f.z), h3 = f2bf(f.w);
    short4v hv = { (short)h0, (short)h1, (short)h2, (short)h3 };
    short4v lv = { (short)f2bf(f.x - bf2f(h0)), (short)f2bf(f.y - bf2f(h1)),
                   (short)f2bf(f.z - bf2f(h2)), (short)f2bf(f.w - bf2f(h3)) };
    const int chunk = code >> 7, cc = code & 127, tile = cc >> 4, cl = cc & 15;
    const int g = (d0 & 31) >> 3, j0 = d0 & 7, secH = (d0 >= 32) ? 1 : 0;
    const int base = chunk * 16384 + tile * 512 + g * 128 + cl * 8 + j0;
    *(short4v*)&ebuf[base + secH * 4096]       = hv;
    *(short4v*)&ebuf[base + (2 + secH) * 4096] = lv;
    float pe = f.x * f.x + f.y * f.y + f.z * f.z + f.w * f.w;
    pe += __shfl_xor(pe, 1);
    pe += __shfl_xor(pe, 2);
    pe += __shfl_xor(pe, 4);
    pe += __shfl_xor(pe, 8);
    if (q == 0) esq[code] = pe;
}

// ---------------- main ----------------
__global__ __launch_bounds__(TPB, 4) void vq_main(
    const float* __restrict__ x, const float* __restrict__ emb,
    const short* __restrict__ ebuf, const float* __restrict__ esq,
    float* __restrict__ enc, float* __restrict__ quant)
{
    __shared__ short s_e[16384];                  // 32 KB chunk buffer
    __shared__ float s_esq[K];                    // 2 KB (lgkm-domain eq reads)
    __shared__ float s_tbs[2][PIXB], s_tss[2][PIXB];
    __shared__ int   s_tbi[2][PIXB], s_tsi[2][PIXB];
    __shared__ int   s_idx[PIXB];

    const int tid  = threadIdx.x;
    const int lane = tid & 63;
    const int wave = __builtin_amdgcn_readfirstlane(tid >> 6);
    const int g    = lane >> 4;
    const int cl   = lane & 15;
    const int ph   = wave & 1;                    // pixel half (32 px)
    const int kh   = wave >> 1;                   // K half (tiles 0-3 / 4-7)
    const int wloc = ph * 32;

    // co-resident blocks under round-robin dispatch differ in bid>>8
    const int phase = (blockIdx.x >> 8) & 3;

    const int pixbase = blockIdx.x * PIXB;
    const int b   = pixbase >> 12;
    const int hw0 = pixbase & (HW - 1);
    const float* xb = x + (size_t)b * D * HW;

    // ---- prologue loads: x (oldest), esq, first-chunk prefetch. NO stores yet. ----
    float xv0[16], xv1[16];
    #pragma unroll
    for (int j = 0; j < 8; ++j) {
        const size_t o0 = (size_t)(g * 8 + j) * HW + hw0 + wloc + cl;
        const size_t o1 = (size_t)(32 + g * 8 + j) * HW + hw0 + wloc + cl;
        xv0[j]     = xb[o0];       xv0[8 + j] = xb[o1];
        xv1[j]     = xb[o0 + 16];  xv1[8 + j] = xb[o1 + 16];
    }
    const float eq_a = esq[tid];
    const float eq_b = esq[tid + 256];

    const bf16x8* gsrc = (const bf16x8*)ebuf;     // 16B units; chunk stride 2048
    bf16x8 stg[8];
    #pragma unroll
    for (int i = 0; i < 8; ++i) stg[i] = gsrc[phase * 2048 + i * 256 + tid];

    // esq -> LDS (waits only its own loads; no stores queued yet)
    s_esq[tid]       = eq_a;
    s_esq[tid + 256] = eq_b;

    // ---- pack A fragments hi/lo (waits x loads; stg stays in flight) ----
    bf16x8 a0h0, a0h1, a0l0, a0l1, a1h0, a1h1, a1l0, a1l1;
    #pragma unroll
    for (int j = 0; j < 8; ++j) {
        unsigned short h;
        h = f2bf(xv0[j]);     a0h0[j] = (short)h; a0l0[j] = (short)f2bf(xv0[j]     - bf2f(h));
        h = f2bf(xv0[8 + j]); a0h1[j] = (short)h; a0l1[j] = (short)f2bf(xv0[8 + j] - bf2f(h));
        h = f2bf(xv1[j]);     a1h0[j] = (short)h; a1l0[j] = (short)f2bf(xv1[j]     - bf2f(h));
        h = f2bf(xv1[8 + j]); a1h1[j] = (short)h; a1l1[j] = (short)f2bf(xv1[8 + j] - bf2f(h));
    }

    float bs0[4], ss0[4], bs1[4], ss1[4];
    int   bi0[4], si0[4], bi1[4], si1[4];
    #pragma unroll
    for (int r = 0; r < 4; ++r) {
        bs0[r] = ss0[r] = bs1[r] = ss1[r] = 3.4e38f;
        bi0[r] = si0[r] = bi1[r] = si1[r] = 0x7fffffff;
    }

    bf16x8* se8 = (bf16x8*)s_e;
    float4* encb4 = (float4*)(enc + (size_t)pixbase * K);
    const float4 z4 = {0.f, 0.f, 0.f, 0.f};

    for (int ci = 0; ci < NCHUNK; ++ci) {
        const int chunk = (ci + phase) & 3;       // rotated chunk order per phase

        // ---- stage regs -> LDS (conflict-free contiguous b128) ----
        #pragma unroll
        for (int i = 0; i < 8; ++i) se8[i * 256 + tid] = stg[i];
        __syncthreads();                           // LDS visible + store pacing drain

        // ---- issue next-chunk prefetch FIRST (older than this chunk's stores) ----
        if (ci + 1 < NCHUNK) {
            const int nxt = (ci + 1 + phase) & 3;
            #pragma unroll
            for (int i = 0; i < 8; ++i)
                stg[i] = gsrc[nxt * 2048 + i * 256 + tid];
        }
        __builtin_amdgcn_sched_barrier(0);
        // ---- then this chunk's one-hot zero slice (32 KB/block, fire-and-forget) ----
        #pragma unroll
        for (int it = 0; it < 8; ++it)
            encb4[chunk * 2048 + it * 256 + tid] = z4;
        __builtin_amdgcn_sched_barrier(0);

        // ---- compute 4 tiles (LDS/MFMA/VALU only; stores drain underneath) ----
        #pragma unroll
        for (int tt = 0; tt < 4; ++tt) {
            const int t8 = kh * 4 + tt;
            const short* pb = s_e + t8 * 512 + g * 128 + cl * 8;
            bf16x8 bh0 = *(const bf16x8*)pb;
            bf16x8 bh1 = *(const bf16x8*)(pb + 4096);
            bf16x8 bl0 = *(const bf16x8*)(pb + 8192);
            bf16x8 bl1 = *(const bf16x8*)(pb + 12288);
            f32x4 c0 = {0.f, 0.f, 0.f, 0.f};
            f32x4 c1 = {0.f, 0.f, 0.f, 0.f};
            c0 = __builtin_amdgcn_mfma_f32_16x16x32_bf16(a0h0, bh0, c0, 0, 0, 0);
            c1 = __builtin_amdgcn_mfma_f32_16x16x32_bf16(a1h0, bh0, c1, 0, 0, 0);
            c0 = __builtin_amdgcn_mfma_f32_16x16x32_bf16(a0h1, bh1, c0, 0, 0, 0);
            c1 = __builtin_amdgcn_mfma_f32_16x16x32_bf16(a1h1, bh1, c1, 0, 0, 0);
            c0 = __builtin_amdgcn_mfma_f32_16x16x32_bf16(a0l0, bh0, c0, 0, 0, 0);
            c1 = __builtin_amdgcn_mfma_f32_16x16x32_bf16(a1l0, bh0, c1, 0, 0, 0);
            c0 = __builtin_amdgcn_mfma_f32_16x16x32_bf16(a0l1, bh1, c0, 0, 0, 0);
            c1 = __builtin_amdgcn_mfma_f32_16x16x32_bf16(a1l1, bh1, c1, 0, 0, 0);
            c0 = __builtin_amdgcn_mfma_f32_16x16x32_bf16(a0h0, bl0, c0, 0, 0, 0);
            c1 = __builtin_amdgcn_mfma_f32_16x16x32_bf16(a1h0, bl0, c1, 0, 0, 0);
            c0 = __builtin_amdgcn_mfma_f32_16x16x32_bf16(a0h1, bl1, c0, 0, 0, 0);
            c1 = __builtin_amdgcn_mfma_f32_16x16x32_bf16(a1h1, bl1, c1, 0, 0, 0);
            const int code = chunk * 128 + t8 * 16 + cl;
            const float eq = s_esq[code];          // lgkm-domain: no store wait
            #pragma unroll
            for (int r = 0; r < 4; ++r) {
                top2u(fmaf(-2.0f, c0[r], eq), code, bs0[r], ss0[r], bi0[r], si0[r]);
                top2u(fmaf(-2.0f, c1[r], eq), code, bs1[r], ss1[r], bi1[r], si1[r]);
            }
        }
        __syncthreads();                           // reads done + store pacing drain
    }

    // ---- cross-lane top-2 merge (over cl within each g-group) ----
    #pragma unroll
    for (int r = 0; r < 4; ++r) {
        for (int m = 1; m <= 8; m <<= 1) {
            float obs, oss; int obi, osi;
            obs = __shfl_xor(bs0[r], m); obi = __shfl_xor(bi0[r], m);
            oss = __shfl_xor(ss0[r], m); osi = __shfl_xor(si0[r], m);
            top2_ins(obs, obi, bs0[r], ss0[r], bi0[r], si0[r]);
            top2_ins(oss, osi, bs0[r], ss0[r], bi0[r], si0[r]);
            obs = __shfl_xor(bs1[r], m); obi = __shfl_xor(bi1[r], m);
            oss = __shfl_xor(ss1[r], m); osi = __shfl_xor(si1[r], m);
            top2_ins(obs, obi, bs1[r], ss1[r], bi1[r], si1[r]);
            top2_ins(oss, osi, bs1[r], ss1[r], bi1[r], si1[r]);
        }
    }
    if (cl == 0) {
        #pragma unroll
        for (int r = 0; r < 4; ++r) {
            const int p0 = wloc + g * 4 + r;          // C/D row = (lane>>4)*4+reg
            s_tbs[kh][p0] = bs0[r]; s_tss[kh][p0] = ss0[r];
            s_tbi[kh][p0] = bi0[r]; s_tsi[kh][p0] = si0[r];
            const int p1 = p0 + 16;
            s_tbs[kh][p1] = bs1[r]; s_tss[kh][p1] = ss1[r];
            s_tbi[kh][p1] = bi1[r]; s_tsi[kh][p1] = si1[r];
        }
    }
    __syncthreads();

    // ---- combine K halves + fp64 refinement of near-ties ----
    if (tid < PIXB) {
        float bs = s_tbs[0][tid], ss = s_tss[0][tid];
        int   bi = s_tbi[0][tid], si = s_tsi[0][tid];
        top2_ins(s_tbs[1][tid], s_tbi[1][tid], bs, ss, bi, si);
        top2_ins(s_tss[1][tid], s_tsi[1][tid], bs, ss, bi, si);
        int fin = bi;
        if (ss - bs < 0.125f) {
            const float* xq = xb + hw0 + tid;
            const float* e0 = emb + (size_t)bi * D;
            const float* e1 = emb + (size_t)si * D;
            double sa = 0.0, sb = 0.0;
            for (int d = 0; d < D; ++d) {
                double xvv = (double)xq[(size_t)d * HW];
                double ev0 = (double)e0[d];
                double ev1 = (double)e1[d];
                sa += ev0 * (ev0 - 2.0 * xvv);
                sb += ev1 * (ev1 - 2.0 * xvv);
            }
            if (sb < sa || (sb == sa && si < bi)) fin = si;
        }
        s_idx[tid] = fin;
    }
    __syncthreads();   // zeros retired + s_idx visible

    // ---- 1.0 scatter ----
    if (tid < PIXB)
        enc[(size_t)(pixbase + tid) * K + s_idx[tid]] = 1.0f;

    // ---- quant writes: coalesced per-channel segments ----
    {
        const int p   = tid & 63;
        const int ch0 = (tid >> 6) * 16;
        const int id  = s_idx[p];
        float* qb = quant + (size_t)b * D * HW + hw0 + p;
        #pragma unroll
        for (int j = 0; j < 16; ++j)
            qb[(size_t)(ch0 + j) * HW] = emb[(size_t)id * D + ch0 + j];
    }
}

extern "C" void kernel_launch(void* const* d_in, const int* in_sizes, int n_in,
                              void* d_out, int out_size, void* d_ws, size_t ws_size,
                              hipStream_t stream)
{
    const float* x   = (const float*)d_in[0];
    const float* emb = (const float*)d_in[1];
    float* enc   = (float*)d_out;
    float* quant = (float*)d_out + (size_t)N * K;

    short* ebuf = (short*)d_ws;                          // 128 KB frag-ordered hi/lo
    float* esq  = (float*)(ebuf + (size_t)K * D * 2);    // 2 KB

    hipLaunchKernelGGL(vq_prep, dim3(K * D / 4 / TPB), dim3(TPB), 0, stream,
                       emb, ebuf, esq);
    hipLaunchKernelGGL(vq_main, dim3(N / PIXB), dim3(TPB), 0, stream,
                       x, emb, ebuf, esq, enc, quant);
}